// Round 12
// baseline (174.926 us; speedup 1.0000x reference)
//
#include <hip/hip_runtime.h>

// LSTM_WP: B=4096 batch-1 LSTMs, T=H=128, input_size=1, fused MFMA-f16 recurrence.
// Round 12: trans-rate probe on the r8 skeleton (fastest: 120.5 us).
// r11 (accidental 1-wave/SIMD test) showed +5% only -> step time is a single-wave
// serial chain (issue-sum + latency), phase-locked at the barrier. The one
// unmeasured constant is the v_exp/v_rcp issue rate. This round cuts trans/row
// 7 -> 6 by replacing the DEPENDENT-chain tanh(c') exp with a Pade(7,6)
// rational (clamp +-5, |err|<=1e-4; c bounded by gate saturation), folding
// sigma(o) into the already-paid rcp. If dur drops >=4%: trans is slower than
// 1/4-rate -> rationalize further next round. If neutral: arithmetic + structure
// both floored -> structural ceiling.

#define H   128
#define T   128
#define BLOCK 512
#define HSTRIDE 136     // f16 per h row: 272 B -> b128-aligned, 2-way banks (free)
#define XSTRIDE 20      // f32 per xs row: 80 B, b128-aligned float4 reads
#define LOG2E    1.44269504088896340736f
#define TWOLOG2E 2.88539008177792681472f

typedef _Float16 f16x8 __attribute__((ext_vector_type(8)));
typedef float    f32x4 __attribute__((ext_vector_type(4)));

// ---- prep: W_hh f32 [512][128] -> f16 fragment-contiguous, log2e-pre-scaled ----
// layout: idx(ct,g,kc,q,l15) = (((ct*4+g)*4+kc)*4+q)*16+l15, 8 f16 each (16 B).
__global__ void prep_whh_kernel(const float* __restrict__ W_hh, _Float16* __restrict__ wfrag)
{
    int idx = blockIdx.x * blockDim.x + threadIdx.x;     // 0..8191
    int l15 =  idx        & 15;
    int q   = (idx >> 4)  & 3;
    int kc  = (idx >> 6)  & 3;
    int g   = (idx >> 8)  & 3;
    int ct  = (idx >> 10) & 7;
    int n  = g * H + ct * 16 + l15;                      // gate row in [0,512)
    int k0 = kc * 32 + q * 8;
    float s = (g == 2) ? TWOLOG2E : LOG2E;
    const float* src = W_hh + (size_t)n * H + k0;
    f16x8 f;
    #pragma unroll
    for (int i = 0; i < 8; ++i) f[i] = (_Float16)(src[i] * s);
    *(f16x8*)(wfrag + (size_t)idx * 8) = f;
}

__device__ __forceinline__ float frcp(float v)  { return __builtin_amdgcn_rcpf(v); }
__device__ __forceinline__ float fexp2(float v) { return __builtin_amdgcn_exp2f(v); }

// ---- one full LSTM step for 16 batches x this wave's 16 cols ----
__device__ __forceinline__ void lstm_step(const _Float16* hr, _Float16* hw,
                                          const float* xp,
                                          const f16x8 wf[4][4],
                                          const float* wihs, const float* biass,
                                          float* c, int l15, int q, int jcol)
{
    // A-fragments: m(batch)=l15, k = kc*32 + q*8 + i (4x ds_read_b128, imm offsets)
    const _Float16* ar = hr + l15 * HSTRIDE + q * 8;
    f16x8 af0 = *(const f16x8*)(ar);
    f16x8 af1 = *(const f16x8*)(ar + 32);
    f16x8 af2 = *(const f16x8*)(ar + 64);
    f16x8 af3 = *(const f16x8*)(ar + 96);

    // preacts (log2 domain for i,f,o; 2*log2e-scaled for g): one b128 xs read
    float4 xl = *(const float4*)xp;
    f32x4 acc[4];
    #pragma unroll
    for (int g = 0; g < 4; ++g) {
        f32x4 iv;
        iv[0] = fmaf(xl.x, wihs[g], biass[g]);
        iv[1] = fmaf(xl.y, wihs[g], biass[g]);
        iv[2] = fmaf(xl.z, wihs[g], biass[g]);
        iv[3] = fmaf(xl.w, wihs[g], biass[g]);
        acc[g] = __builtin_amdgcn_mfma_f32_16x16x32_f16(af0, wf[g][0], iv, 0, 0, 0);
    }
    #pragma unroll
    for (int g = 0; g < 4; ++g)
        acc[g] = __builtin_amdgcn_mfma_f32_16x16x32_f16(af1, wf[g][1], acc[g], 0, 0, 0);
    #pragma unroll
    for (int g = 0; g < 4; ++g)
        acc[g] = __builtin_amdgcn_mfma_f32_16x16x32_f16(af2, wf[g][2], acc[g], 0, 0, 0);
    #pragma unroll
    for (int g = 0; g < 4; ++g)
        acc[g] = __builtin_amdgcn_mfma_f32_16x16x32_f16(af3, wf[g][3], acc[g], 0, 0, 0);

    // ---- ew phase 1: all 16 independent exps ----
    float Ei[4], Ef[4], Eg[4], Eo[4];
    #pragma unroll
    for (int r = 0; r < 4; ++r) {
        Ei[r] = fexp2(-acc[0][r]);       // sigmoid_i = 1/(1+Ei)
        Ef[r] = fexp2(-acc[1][r]);       // sigmoid_f = 1/(1+Ef)
        Eg[r] = fexp2( acc[2][r]);       // tanh_g    = (Eg-1)/(Eg+1)
        Eo[r] = fexp2(-acc[3][r]);       // sigmoid_o = 1/(1+Eo)
    }
    // ---- ew phase 2: fused-rcp c update + RATIONAL tanh(c') (no dependent exp) ----
    _Float16* hwp = hw + (q * 4) * HSTRIDE + jcol;
    #pragma unroll
    for (int r = 0; r < 4; ++r) {
        float u  = 1.0f + Ei[r];
        float v  = 1.0f + Ef[r];
        float w  = 1.0f + Eg[r];
        float wm = Eg[r] - 1.0f;
        float uw = u * w;
        // c' = c/v + wm/(u*w) = [c*u*w + wm*v] / (v*u*w), one rcp
        float cn = fmaf(c[r], uw, wm * v) * frcp(v * uw);
        c[r] = cn;
        // tanh(c') via Pade(7,6): x(x^6+378x^4+17325x^2+135135) /
        //                          (28x^6+3150x^4+62370x^2+135135), clamp +-5
        // |err| <= 1e-4 over the clamped range (checked x=1,2,4,5).
        float xc = fminf(fmaxf(cn, -5.0f), 5.0f);
        float s2 = xc * xc;
        float nt = xc * fmaf(fmaf(s2 + 378.0f, s2, 17325.0f), s2, 135135.0f);
        float dt = fmaf(fmaf(fmaf(28.0f, s2, 3150.0f), s2, 62370.0f), s2, 135135.0f);
        // h = tanh(c') * sigmoid(o): fold sigma_o into the same rcp
        float hv = nt * frcp(dt * (1.0f + Eo[r]));
        hwp[r * HSTRIDE] = (_Float16)hv;
    }
}

__launch_bounds__(BLOCK, 2)
__global__ void lstm_fused_kernel(const float* __restrict__ x,
                                  const float* __restrict__ W_ih,
                                  const _Float16* __restrict__ wfrag,
                                  const float* __restrict__ b_ih,
                                  const float* __restrict__ b_hh,
                                  const float* __restrict__ fc_W,
                                  const float* __restrict__ fc_b,
                                  float* __restrict__ out)
{
    __shared__ __align__(16) float xs[T][XSTRIDE];               // 10 KB
    __shared__ __align__(16) _Float16 hb0[16 * HSTRIDE];         // h buffers (4.25 KB each)
    __shared__ __align__(16) _Float16 hb1[16 * HSTRIDE];

    const int tid  = threadIdx.x;
    const int wave = tid >> 6;          // column tile 0..7
    const int lane = tid & 63;
    const int l15  = lane & 15;
    const int q    = lane >> 4;         // 0..3
    const int jcol = wave * 16 + l15;   // hidden column 0..127

    // ---- stage x: [b][t] global -> xs[t][b] (16 batches x 128 t) ----
    {
        const int t0 = tid & 127;
        const int bb = tid >> 7;        // 0..3
        const float* xb = x + (size_t)blockIdx.x * (16 * T);
        xs[t0][bb]      = xb[bb * T + t0];
        xs[t0][bb + 4]  = xb[(bb + 4) * T + t0];
        xs[t0][bb + 8]  = xb[(bb + 8) * T + t0];
        xs[t0][bb + 12] = xb[(bb + 12) * T + t0];
    }
    for (int i = tid; i < 16 * HSTRIDE; i += BLOCK)              // h0 = 0
        hb0[i] = (_Float16)0.0f;

    // ---- weights: this wave's 16 gate-cols as f16 fragments (64 VGPRs) ----
    f16x8 wf[4][4];
    float wihs[4], biass[4];
    {
        const _Float16* wbase = wfrag + (size_t)wave * 8192;
        #pragma unroll
        for (int g = 0; g < 4; ++g) {
            const int n = g * H + jcol;
            const float s = (g == 2) ? TWOLOG2E : LOG2E;
            wihs[g]  = W_ih[n] * s;
            biass[g] = (b_ih[n] + b_hh[n]) * s;
            #pragma unroll
            for (int kc = 0; kc < 4; ++kc)
                wf[g][kc] = *(const f16x8*)(wbase + ((((g * 4 + kc) * 4 + q) * 16 + l15) * 8));
        }
    }

    float c[4] = {0.f, 0.f, 0.f, 0.f};
    const float* xp = &xs[0][q * 4];

    __syncthreads();

    // ---- recurrence: unrolled x2, compile-time buffer bases, 1 barrier/step ----
    #pragma unroll 1
    for (int t2 = 0; t2 < T / 2; ++t2) {
        lstm_step(hb0, hb1, xp, wf, wihs, biass, c, l15, q, jcol);
        xp += XSTRIDE;
        __syncthreads();
        lstm_step(hb1, hb0, xp, wf, wihs, biass, c, l15, q, jcol);
        xp += XSTRIDE;
        __syncthreads();
    }
    // T even -> final h lives in hb0

    // ---- epilogue: out[b] = fc_b + sum_j fc_W[j] * hT[b][j] ----
    if (tid < 256) {
        const int b    = tid >> 4;      // 0..15
        const int part = tid & 15;
        const _Float16* hrow = &hb0[b * HSTRIDE];
        float s = 0.0f;
        #pragma unroll
        for (int i = 0; i < 8; ++i) {
            const int j = part * 8 + i;
            s += fc_W[j] * (float)hrow[j];
        }
        s += __shfl_xor(s, 8, 16);
        s += __shfl_xor(s, 4, 16);
        s += __shfl_xor(s, 2, 16);
        s += __shfl_xor(s, 1, 16);
        if (part == 0)
            out[blockIdx.x * 16 + b] = s + fc_b[0];
    }
}

extern "C" void kernel_launch(void* const* d_in, const int* in_sizes, int n_in,
                              void* d_out, int out_size, void* d_ws, size_t ws_size,
                              hipStream_t stream)
{
    const float* x    = (const float*)d_in[0];
    const float* W_ih = (const float*)d_in[1];
    const float* W_hh = (const float*)d_in[2];
    const float* b_ih = (const float*)d_in[3];
    const float* b_hh = (const float*)d_in[4];
    const float* fc_W = (const float*)d_in[5];
    const float* fc_b = (const float*)d_in[6];
    float* out = (float*)d_out;

    _Float16* wfrag = (_Float16*)d_ws;     // 64K f16 = 128 KB fragment-ordered, log2e-scaled

    hipLaunchKernelGGL(prep_whh_kernel, dim3(32), dim3(256), 0, stream, W_hh, wfrag);

    const int B = in_sizes[0] / H;         // 4096 chunks
    dim3 grid(B / 16);                     // 256 blocks -> 1 per CU
    dim3 block(BLOCK);                     // 8 waves, 2 per SIMD
    hipLaunchKernelGGL(lstm_fused_kernel, grid, block, 0, stream,
                       x, W_ih, wfrag, b_ih, b_hh, fc_W, fc_b, out);
}

// Round 13
// 169.074 us; speedup vs baseline: 1.0346x; 1.0346x over previous
//
#include <hip/hip_runtime.h>

// LSTM_WP: B=4096 batch-1 LSTMs, T=H=128, input_size=1, fused MFMA-f16 recurrence.
// FINAL (= round-8 kernel, best measured: 120.3-120.7 us over two benches).
// Structure: 256 blocks x 16 batches (one M=16 MFMA tile per CU -- batch dim
// exhausted), 8 waves, wave = 16 gate-cols, 16 MFMAs/wave/step, 1 barrier/step.
// Key elements (each HW-verified in rounds 1-12):
//  - W_hh pre-converted once to f16 MFMA B-fragments, log2e-folded (gate g by
//    2*log2e) -> activations are raw v_exp_f32 ops in the log2 domain.
//  - h round-trips through LDS (272 B row stride: b128-aligned, 2-way banks).
//  - fused-rcp gate algebra: 5 exp + 2 rcp per row (r12 proved trading the
//    dependent exp for VALU regresses; trans issue at 1/4 rate).
//  - t-loop unrolled x2 over two LDS buffers -> compile-time addresses.
// Ceiling evidence: duplication overlap (r2/r5/r6/r7), zero-dup overlap
// (r9/r11), latency arrangement (r10), arithmetic trades (r12) all neutral or
// regressive -> per-step wall ~940 ns is the serial all-to-all recurrence
// chain: barrier + ds_read latency + MFMA issue/tail + 224 cyc trans + drain.

#define H   128
#define T   128
#define BLOCK 512
#define HSTRIDE 136     // f16 per h row: 272 B -> b128-aligned, 2-way banks (free)
#define XSTRIDE 20      // f32 per xs row: 80 B, b128-aligned float4 reads
#define LOG2E    1.44269504088896340736f
#define TWOLOG2E 2.88539008177792681472f

typedef _Float16 f16x8 __attribute__((ext_vector_type(8)));
typedef float    f32x4 __attribute__((ext_vector_type(4)));

// ---- prep: W_hh f32 [512][128] -> f16 fragment-contiguous, log2e-pre-scaled ----
// layout: idx(ct,g,kc,q,l15) = (((ct*4+g)*4+kc)*4+q)*16+l15, 8 f16 each (16 B).
__global__ void prep_whh_kernel(const float* __restrict__ W_hh, _Float16* __restrict__ wfrag)
{
    int idx = blockIdx.x * blockDim.x + threadIdx.x;     // 0..8191
    int l15 =  idx        & 15;
    int q   = (idx >> 4)  & 3;
    int kc  = (idx >> 6)  & 3;
    int g   = (idx >> 8)  & 3;
    int ct  = (idx >> 10) & 7;
    int n  = g * H + ct * 16 + l15;                      // gate row in [0,512)
    int k0 = kc * 32 + q * 8;
    float s = (g == 2) ? TWOLOG2E : LOG2E;
    const float* src = W_hh + (size_t)n * H + k0;
    f16x8 f;
    #pragma unroll
    for (int i = 0; i < 8; ++i) f[i] = (_Float16)(src[i] * s);
    *(f16x8*)(wfrag + (size_t)idx * 8) = f;
}

__device__ __forceinline__ float frcp(float v)  { return __builtin_amdgcn_rcpf(v); }
__device__ __forceinline__ float fexp2(float v) { return __builtin_amdgcn_exp2f(v); }

// ---- one full LSTM step for 16 batches x this wave's 16 cols ----
__device__ __forceinline__ void lstm_step(const _Float16* hr, _Float16* hw,
                                          const float* xp,
                                          const f16x8 wf[4][4],
                                          const float* wihs, const float* biass,
                                          float* c, int l15, int q, int jcol)
{
    // A-fragments: m(batch)=l15, k = kc*32 + q*8 + i (4x ds_read_b128, imm offsets)
    const _Float16* ar = hr + l15 * HSTRIDE + q * 8;
    f16x8 af0 = *(const f16x8*)(ar);
    f16x8 af1 = *(const f16x8*)(ar + 32);
    f16x8 af2 = *(const f16x8*)(ar + 64);
    f16x8 af3 = *(const f16x8*)(ar + 96);

    // preacts (log2 domain): x*W_ih + b, rows b = q*4+r (one b128 xs read)
    float4 xl = *(const float4*)xp;
    f32x4 acc[4];
    #pragma unroll
    for (int g = 0; g < 4; ++g) {
        f32x4 iv;
        iv[0] = fmaf(xl.x, wihs[g], biass[g]);
        iv[1] = fmaf(xl.y, wihs[g], biass[g]);
        iv[2] = fmaf(xl.z, wihs[g], biass[g]);
        iv[3] = fmaf(xl.w, wihs[g], biass[g]);
        acc[g] = __builtin_amdgcn_mfma_f32_16x16x32_f16(af0, wf[g][0], iv, 0, 0, 0);
    }
    #pragma unroll
    for (int g = 0; g < 4; ++g)
        acc[g] = __builtin_amdgcn_mfma_f32_16x16x32_f16(af1, wf[g][1], acc[g], 0, 0, 0);
    #pragma unroll
    for (int g = 0; g < 4; ++g)
        acc[g] = __builtin_amdgcn_mfma_f32_16x16x32_f16(af2, wf[g][2], acc[g], 0, 0, 0);
    #pragma unroll
    for (int g = 0; g < 4; ++g)
        acc[g] = __builtin_amdgcn_mfma_f32_16x16x32_f16(af3, wf[g][3], acc[g], 0, 0, 0);

    // ---- ew phase 1: all 16 independent exps (saturate trans pipe) ----
    float Ei[4], Ef[4], Eg[4], Eo[4];
    #pragma unroll
    for (int r = 0; r < 4; ++r) {
        Ei[r] = fexp2(-acc[0][r]);       // sigmoid_i = 1/(1+Ei)
        Ef[r] = fexp2(-acc[1][r]);       // sigmoid_f = 1/(1+Ef)
        Eg[r] = fexp2( acc[2][r]);       // tanh_g    = (Eg-1)/(Eg+1)
        Eo[r] = fexp2(-acc[3][r]);       // sigmoid_o = 1/(1+Eo)
    }
    // ---- ew phase 2: fused-rcp c/h updates + dependent tanh(c) exps ----
    _Float16* hwp = hw + (q * 4) * HSTRIDE + jcol;
    #pragma unroll
    for (int r = 0; r < 4; ++r) {
        float u  = 1.0f + Ei[r];
        float v  = 1.0f + Ef[r];
        float w  = 1.0f + Eg[r];
        float wm = Eg[r] - 1.0f;
        float uw = u * w;
        // c' = c/v + wm/(u*w) = [c*u*w + wm*v] / (v*u*w), one rcp
        float cn = fmaf(c[r], uw, wm * v) * frcp(v * uw);
        c[r] = cn;
        float Ec = fexp2(cn * TWOLOG2E); // tanh(c') = (Ec-1)/(Ec+1)
        float hv = (Ec - 1.0f) * frcp((Ec + 1.0f) * (1.0f + Eo[r]));
        hwp[r * HSTRIDE] = (_Float16)hv;
    }
}

__launch_bounds__(BLOCK, 2)
__global__ void lstm_fused_kernel(const float* __restrict__ x,
                                  const float* __restrict__ W_ih,
                                  const _Float16* __restrict__ wfrag,
                                  const float* __restrict__ b_ih,
                                  const float* __restrict__ b_hh,
                                  const float* __restrict__ fc_W,
                                  const float* __restrict__ fc_b,
                                  float* __restrict__ out)
{
    __shared__ __align__(16) float xs[T][XSTRIDE];               // 10 KB
    __shared__ __align__(16) _Float16 hb0[16 * HSTRIDE];         // h buffers (4.25 KB each)
    __shared__ __align__(16) _Float16 hb1[16 * HSTRIDE];

    const int tid  = threadIdx.x;
    const int wave = tid >> 6;          // column tile 0..7
    const int lane = tid & 63;
    const int l15  = lane & 15;
    const int q    = lane >> 4;         // 0..3
    const int jcol = wave * 16 + l15;   // hidden column 0..127

    // ---- stage x: [b][t] global -> xs[t][b] (16 batches x 128 t) ----
    {
        const int t0 = tid & 127;
        const int bb = tid >> 7;        // 0..3
        const float* xb = x + (size_t)blockIdx.x * (16 * T);
        xs[t0][bb]      = xb[bb * T + t0];
        xs[t0][bb + 4]  = xb[(bb + 4) * T + t0];
        xs[t0][bb + 8]  = xb[(bb + 8) * T + t0];
        xs[t0][bb + 12] = xb[(bb + 12) * T + t0];
    }
    for (int i = tid; i < 16 * HSTRIDE; i += BLOCK)              // h0 = 0
        hb0[i] = (_Float16)0.0f;

    // ---- weights: this wave's 16 gate-cols as f16 fragments (64 VGPRs) ----
    f16x8 wf[4][4];
    float wihs[4], biass[4];
    {
        const _Float16* wbase = wfrag + (size_t)wave * 8192;
        #pragma unroll
        for (int g = 0; g < 4; ++g) {
            const int n = g * H + jcol;
            const float s = (g == 2) ? TWOLOG2E : LOG2E;
            wihs[g]  = W_ih[n] * s;
            biass[g] = (b_ih[n] + b_hh[n]) * s;
            #pragma unroll
            for (int kc = 0; kc < 4; ++kc)
                wf[g][kc] = *(const f16x8*)(wbase + ((((g * 4 + kc) * 4 + q) * 16 + l15) * 8));
        }
    }

    float c[4] = {0.f, 0.f, 0.f, 0.f};
    const float* xp = &xs[0][q * 4];

    __syncthreads();

    // ---- recurrence: unrolled x2, compile-time buffer bases, 1 barrier/step ----
    #pragma unroll 1
    for (int t2 = 0; t2 < T / 2; ++t2) {
        lstm_step(hb0, hb1, xp, wf, wihs, biass, c, l15, q, jcol);
        xp += XSTRIDE;
        __syncthreads();
        lstm_step(hb1, hb0, xp, wf, wihs, biass, c, l15, q, jcol);
        xp += XSTRIDE;
        __syncthreads();
    }
    // T even -> final h lives in hb0

    // ---- epilogue: out[b] = fc_b + sum_j fc_W[j] * hT[b][j] ----
    if (tid < 256) {
        const int b    = tid >> 4;      // 0..15
        const int part = tid & 15;
        const _Float16* hrow = &hb0[b * HSTRIDE];
        float s = 0.0f;
        #pragma unroll
        for (int i = 0; i < 8; ++i) {
            const int j = part * 8 + i;
            s += fc_W[j] * (float)hrow[j];
        }
        s += __shfl_xor(s, 8, 16);
        s += __shfl_xor(s, 4, 16);
        s += __shfl_xor(s, 2, 16);
        s += __shfl_xor(s, 1, 16);
        if (part == 0)
            out[blockIdx.x * 16 + b] = s + fc_b[0];
    }
}

extern "C" void kernel_launch(void* const* d_in, const int* in_sizes, int n_in,
                              void* d_out, int out_size, void* d_ws, size_t ws_size,
                              hipStream_t stream)
{
    const float* x    = (const float*)d_in[0];
    const float* W_ih = (const float*)d_in[1];
    const float* W_hh = (const float*)d_in[2];
    const float* b_ih = (const float*)d_in[3];
    const float* b_hh = (const float*)d_in[4];
    const float* fc_W = (const float*)d_in[5];
    const float* fc_b = (const float*)d_in[6];
    float* out = (float*)d_out;

    _Float16* wfrag = (_Float16*)d_ws;     // 64K f16 = 128 KB fragment-ordered, log2e-scaled

    hipLaunchKernelGGL(prep_whh_kernel, dim3(32), dim3(256), 0, stream, W_hh, wfrag);

    const int B = in_sizes[0] / H;         // 4096 chunks
    dim3 grid(B / 16);                     // 256 blocks -> 1 per CU
    dim3 block(BLOCK);                     // 8 waves, 2 per SIMD
    hipLaunchKernelGGL(lstm_fused_kernel, grid, block, 0, stream,
                       x, W_ih, wfrag, b_ih, b_hh, fc_W, fc_b, out);
}